// Round 9
// baseline (32.417 us; speedup 1.0000x reference)
//
#include <hip/hip_runtime.h>

#define B 32
#define L 512
#define D 768
#define M 24
#define P (M * (M - 1))   // 552
#define Q4 (D / 4)        // 192 quads per half-row
#define CHUNKS 8          // K2 blocks per batch
#define ROWS_PER_BLK (P / CHUNKS)   // 69

typedef float f32x4 __attribute__((ext_vector_type(4)));

// K1 (read phase): one block per (b,m), 192 threads. Parallel gather (15
// clamped unconditional loads, masked adds) -> pooled. Threads 0..22 also
// emit the 5-float pair rows.
__global__ void __launch_bounds__(Q4)
pool_kernel(const float* __restrict__ seq,   // B,L,D
            const int*   __restrict__ head,  // B,L
            const int*   __restrict__ em,    // B,M,2
            float*       __restrict__ pooled,// B,M,D
            float*       __restrict__ pout)  // B*P*5
{
    int bm = blockIdx.x;           // 0 .. B*M-1
    int b = bm / M, m = bm - b * M;
    int tq = threadIdx.x;          // 0..191

    int s = em[bm * 2 + 0];
    int e = em[bm * 2 + 1];
    int len = e - s;               // 1..15

    const float* seqb  = seq  + (size_t)b * L * D;
    const int*   headb = head + b * L;

    int hidx[15];
    #pragma unroll
    for (int r = 0; r < 15; ++r) {
        int l = s + r; l = (l < e) ? l : s;   // clamp -> unconditional
        hidx[r] = headb[l];
    }
    f32x4 vv[15];
    #pragma unroll
    for (int r = 0; r < 15; ++r)
        vv[r] = ((const f32x4*)(seqb + (size_t)hidx[r] * D))[tq];
    f32x4 acc = (f32x4)(0.f);
    #pragma unroll
    for (int r = 0; r < 15; ++r)
        acc += (r < len) ? vv[r] : (f32x4)(0.f);
    acc *= 1.0f / (float)len;

    ((f32x4*)pooled)[(size_t)bm * Q4 + tq] = acc;

    if (tq < 23) {
        int r = tq;
        int j = (r < m) ? r : r + 1;
        const int* emb = em + b * M * 2;
        float* o = pout + ((size_t)b * P + (size_t)m * 23 + r) * 5;
        o[0] = (float)b;
        o[1] = (float)s;
        o[2] = (float)e;
        o[3] = (float)emb[2 * j];
        o[4] = (float)emb[2 * j + 1];
    }
}

// K2 (write phase): 256 blocks (8 per batch) x 384 threads. Stage the batch's
// full pooled set (24 x 3KB = 72KB) in LDS, then stream 69 complete rows:
// per row each thread does one LDS read + one regular f32x4 store; the block's
// output range is perfectly sequential (414 KB).
__global__ void __launch_bounds__(2 * Q4)
rel_kernel(const float* __restrict__ pooled,  // B,M,D
           float*       __restrict__ out)     // B*P*1536
{
    __shared__ f32x4 lpool[M * Q4];   // 72 KB

    int blk   = blockIdx.x;           // 0..255
    int b     = blk / CHUNKS;
    int chunk = blk - b * CHUNKS;
    int t     = threadIdx.x;          // 0..383

    // stage pooled[b] -> LDS (4608 quads, 12 per thread, coalesced)
    const f32x4* src = (const f32x4*)pooled + (size_t)b * M * Q4;
    #pragma unroll
    for (int k = 0; k < M * Q4 / (2 * Q4); ++k)     // 12
        lpool[k * 2 * Q4 + t] = src[k * 2 * Q4 + t];
    __syncthreads();

    int p0 = chunk * ROWS_PER_BLK;
    int hf = t >= Q4;                  // 0: obj half, 1: sub half
    int tq = hf ? t - Q4 : t;

    f32x4* dst = (f32x4*)out + ((size_t)b * P + p0) * 384 + t;

    for (int pr = 0; pr < ROWS_PER_BLK; ++pr) {
        int p = p0 + pr;
        int i = p / 23;                // magic-mul
        int r = p - i * 23;
        int j = (r < i) ? r : r + 1;
        int src_m = hf ? j : i;        // wave-uniform
        *dst = lpool[src_m * Q4 + tq];
        dst += 384;
    }
}

extern "C" void kernel_launch(void* const* d_in, const int* in_sizes, int n_in,
                              void* d_out, int out_size, void* d_ws, size_t ws_size,
                              hipStream_t stream) {
    const float* seq  = (const float*)d_in[0];
    const int*   head = (const int*)d_in[1];
    const int*   em   = (const int*)d_in[2];
    float* out    = (float*)d_out;
    float* pooled = (float*)d_ws;                 // B*M*D f32 = 2.36 MB

    pool_kernel<<<B * M, Q4, 0, stream>>>(seq, head, em, pooled,
                                          out + (size_t)B * P * 2 * D);
    rel_kernel<<<B * CHUNKS, 2 * Q4, 0, stream>>>(pooled, out);
}

// Round 10
// 29.360 us; speedup vs baseline: 1.1041x; 1.1041x over previous
//
#include <hip/hip_runtime.h>

#define B 32
#define L 512
#define D 768
#define M 24
#define P (M * (M - 1))   // 552
#define Q4 (D / 4)        // 192 quads per half-row

typedef float f32x4 __attribute__((ext_vector_type(4)));

// 768 blocks x 192 threads. Block = (mention-pair, half-role).
//   half 0: obj role (writes first 768 floats of rows m*23+r) + pair rows
//   half 1: sub role (writes last 768 floats of rows i*23+r(i,m))
// Each block processes mentions m0=2*mp and m1=2*mp+1 of one batch,
// software-pipelined: m1's row loads are issued before m0's store burst.
__global__ void __launch_bounds__(Q4)
fused_kernel(const float* __restrict__ seq,   // B,L,D
             const int*   __restrict__ head,  // B,L
             const int*   __restrict__ em,    // B,M,2
             float*       __restrict__ out)   // B*P*1536 rel | B*P*5 pairs
{
    int blk  = blockIdx.x;          // 0..767
    int half = blk & 1;
    int g    = blk >> 1;            // 0..383 mention-pair id
    int b    = g / (M / 2);
    int mp   = g - b * (M / 2);
    int m0   = 2 * mp, m1 = m0 + 1;
    int tq   = threadIdx.x;         // 0..191

    const float* seqb  = seq  + (size_t)b * L * D;
    const int*   headb = head + b * L;
    const int*   emb   = em   + b * M * 2;

    int s0 = emb[2 * m0], e0 = emb[2 * m0 + 1];
    int s1 = emb[2 * m1], e1 = emb[2 * m1 + 1];
    int len0 = e0 - s0, len1 = e1 - s1;

    // head indexes for BOTH mentions up front (all loads in flight together)
    int h0[15], h1[15];
    #pragma unroll
    for (int r = 0; r < 15; ++r) {
        int l = s0 + r; l = (l < e0) ? l : s0;
        h0[r] = headb[l];
    }
    #pragma unroll
    for (int r = 0; r < 15; ++r) {
        int l = s1 + r; l = (l < e1) ? l : s1;
        h1[r] = headb[l];
    }

    // gather m0
    f32x4 vv[15];
    #pragma unroll
    for (int r = 0; r < 15; ++r)
        vv[r] = ((const f32x4*)(seqb + (size_t)h0[r] * D))[tq];
    f32x4 acc = (f32x4)(0.f);
    #pragma unroll
    for (int r = 0; r < 15; ++r)
        acc += (r < len0) ? vv[r] : (f32x4)(0.f);
    f32x4 v0 = acc * (1.0f / (float)len0);

    // issue m1's row loads BEFORE m0's stores (overlap loads with store burst)
    #pragma unroll
    for (int r = 0; r < 15; ++r)
        vv[r] = ((const f32x4*)(seqb + (size_t)h1[r] * D))[tq];

    f32x4* outq = (f32x4*)out;                   // rel rows: 384 quads each
    float* pout = out + (size_t)B * P * 2 * D;   // pairs region
    size_t rowbase = (size_t)b * P;

    // ---- write mention m0 ----
    if (half == 0) {
        size_t q = (rowbase + (size_t)m0 * 23) * 384 + tq;
        #pragma unroll
        for (int r = 0; r < 23; ++r) {
            __builtin_nontemporal_store(v0, &outq[q]);
            q += 384;
        }
        if (tq < 23) {
            int r = tq;
            int j = (r < m0) ? r : r + 1;
            float* o = pout + (rowbase + (size_t)m0 * 23 + r) * 5;
            o[0] = (float)b; o[1] = (float)s0; o[2] = (float)e0;
            o[3] = (float)emb[2 * j]; o[4] = (float)emb[2 * j + 1];
        }
    } else {
        #pragma unroll
        for (int i = 0; i < M; ++i) {
            if (i == m0) continue;
            int r = (m0 < i) ? m0 : m0 - 1;
            size_t row = rowbase + (size_t)i * 23 + r;
            __builtin_nontemporal_store(v0, &outq[row * 384 + Q4 + tq]);
        }
    }

    // ---- fold m1 (waits on m1 loads; m0 stores still outstanding) ----
    acc = (f32x4)(0.f);
    #pragma unroll
    for (int r = 0; r < 15; ++r)
        acc += (r < len1) ? vv[r] : (f32x4)(0.f);
    f32x4 v1 = acc * (1.0f / (float)len1);

    // ---- write mention m1 ----
    if (half == 0) {
        size_t q = (rowbase + (size_t)m1 * 23) * 384 + tq;
        #pragma unroll
        for (int r = 0; r < 23; ++r) {
            __builtin_nontemporal_store(v1, &outq[q]);
            q += 384;
        }
        if (tq < 23) {
            int r = tq;
            int j = (r < m1) ? r : r + 1;
            float* o = pout + (rowbase + (size_t)m1 * 23 + r) * 5;
            o[0] = (float)b; o[1] = (float)s1; o[2] = (float)e1;
            o[3] = (float)emb[2 * j]; o[4] = (float)emb[2 * j + 1];
        }
    } else {
        #pragma unroll
        for (int i = 0; i < M; ++i) {
            if (i == m1) continue;
            int r = (m1 < i) ? m1 : m1 - 1;
            size_t row = rowbase + (size_t)i * 23 + r;
            __builtin_nontemporal_store(v1, &outq[row * 384 + Q4 + tq]);
        }
    }
}

extern "C" void kernel_launch(void* const* d_in, const int* in_sizes, int n_in,
                              void* d_out, int out_size, void* d_ws, size_t ws_size,
                              hipStream_t stream) {
    const float* seq  = (const float*)d_in[0];
    const int*   head = (const int*)d_in[1];
    const int*   em   = (const int*)d_in[2];
    float* out = (float*)d_out;

    fused_kernel<<<B * M, Q4, 0, stream>>>(seq, head, em, out);   // 768 blocks
}

// Round 11
// 25.821 us; speedup vs baseline: 1.2555x; 1.1371x over previous
//
#include <hip/hip_runtime.h>

#define B 32
#define L 512
#define D 768
#define M 24
#define P (M * (M - 1))   // 552
#define G2 (D / 2)        // 384 float2 granules per half-row

typedef float f32x2 __attribute__((ext_vector_type(2)));

// 1536 blocks x 384 threads. Block = (mention g, half-role).
// Swizzle: g = (blk>>4)*8 + (blk&7), half = (blk>>3)&1 -> a mention's obj and
// sub blocks are 8 apart => same XCD => duplicate gather hits that XCD's L2.
// Thread tq owns the float2 at column 2*tq of the pooled vector:
// gathers it from all span rows (clamped unconditional loads, masked adds),
// then stores it into 23 output half-rows with regular (cached) stores.
// Low VGPR (~64-72) -> ~30 waves/CU to saturate the write stream.
__global__ void __launch_bounds__(G2, 7)
fused_kernel(const float* __restrict__ seq,   // B,L,D
             const int*   __restrict__ head,  // B,L
             const int*   __restrict__ em,    // B,M,2
             float*       __restrict__ out)   // B*P*1536 rel | B*P*5 pairs
{
    int blk  = blockIdx.x;               // 0..1535
    int g    = ((blk >> 4) << 3) + (blk & 7);   // 0..767 mention id
    int half = (blk >> 3) & 1;           // 0: obj, 1: sub
    int b    = g / M, m = g - b * M;
    int tq   = threadIdx.x;              // 0..383

    const float* seqb  = seq  + (size_t)b * L * D;
    const int*   headb = head + b * L;
    const int*   emb   = em   + b * M * 2;

    int s = emb[2 * m];
    int e = emb[2 * m + 1];
    int len = e - s;                     // 1..15

    // parallel gather of this thread's float2 column
    int hidx[15];
    #pragma unroll
    for (int r = 0; r < 15; ++r) {
        int l = s + r; l = (l < e) ? l : s;      // clamp -> unconditional
        hidx[r] = headb[l];
    }
    f32x2 vv[15];
    #pragma unroll
    for (int r = 0; r < 15; ++r)
        vv[r] = ((const f32x2*)(seqb + (size_t)hidx[r] * D))[tq];
    f32x2 acc = (f32x2)(0.f);
    #pragma unroll
    for (int r = 0; r < 15; ++r)
        acc += (r < len) ? vv[r] : (f32x2)(0.f);
    f32x2 v = acc * (1.0f / (float)len);

    f32x2* outg = (f32x2*)out;           // rel rows: 768 f32x2 each
    size_t rowbase = (size_t)b * P;

    if (half == 0) {
        // OBJ: rows m*23 + r, granule tq (first half)
        size_t q = (rowbase + (size_t)m * 23) * 768 + tq;
        #pragma unroll
        for (int r = 0; r < 23; ++r) {
            outg[q] = v;
            q += 768;
        }
        if (tq < 23) {
            int r = tq;
            int j = (r < m) ? r : r + 1;
            float* o = out + (size_t)B * P * 2 * D
                     + (rowbase + (size_t)m * 23 + r) * 5;
            o[0] = (float)b;
            o[1] = (float)s;
            o[2] = (float)e;
            o[3] = (float)emb[2 * j];
            o[4] = (float)emb[2 * j + 1];
        }
    } else {
        // SUB: this mention is j == m; for each i != m, r = (m<i) ? m : m-1
        #pragma unroll
        for (int i = 0; i < M; ++i) {
            if (i == m) continue;
            int r = (m < i) ? m : m - 1;
            size_t row = rowbase + (size_t)i * 23 + r;
            outg[row * 768 + G2 + tq] = v;
        }
    }
}

extern "C" void kernel_launch(void* const* d_in, const int* in_sizes, int n_in,
                              void* d_out, int out_size, void* d_ws, size_t ws_size,
                              hipStream_t stream) {
    const float* seq  = (const float*)d_in[0];
    const int*   head = (const int*)d_in[1];
    const int*   em   = (const int*)d_in[2];
    float* out = (float*)d_out;

    fused_kernel<<<B * M * 2, G2, 0, stream>>>(seq, head, em, out);  // 1536 blocks
}

// Round 12
// 25.560 us; speedup vs baseline: 1.2683x; 1.0102x over previous
//
#include <hip/hip_runtime.h>

#define B 32
#define L 512
#define D 768
#define M 24
#define P (M * (M - 1))   // 552

typedef float f32x2 __attribute__((ext_vector_type(2)));

// 1536 blocks x 384 threads. Block = (mention g, column-half chalf).
// Threads: rp = t>=192 (even/odd gather rows; also store role), c = t-192*rp.
// Global f32x2 column = chalf*192 + c. Gather is fully deduplicated:
// column-halves read disjoint row slices, even/odd threads disjoint rows.
// LDS combine (3 KB) + one barrier, then 23 regular coalesced stores per
// thread (rp=0 -> obj half of rows m*23+r; rp=1 -> sub half of rows i*23+r).
__global__ void __launch_bounds__(384, 8)
fused_kernel(const float* __restrict__ seq,   // B,L,D
             const int*   __restrict__ head,  // B,L
             const int*   __restrict__ em,    // B,M,2
             float*       __restrict__ out)   // B*P*1536 rel | B*P*5 pairs
{
    __shared__ f32x2 pool[2][192];   // 3 KB

    int blk   = blockIdx.x;          // 0..1535
    int g     = blk >> 1;            // mention id 0..767
    int chalf = blk & 1;             // column half
    int b = g / M, m = g - b * M;
    int t  = threadIdx.x;            // 0..383
    int rp = (t >= 192);             // even/odd gather + store role
    int c  = t - rp * 192;           // 0..191
    int col = chalf * 192 + c;       // global f32x2 column 0..383

    const float* seqb  = seq  + (size_t)b * L * D;
    const int*   headb = head + b * L;
    const int*   emb   = em   + b * M * 2;

    int s = emb[2 * m];
    int e = emb[2 * m + 1];
    int len = e - s;                 // 1..15
    int cnt = (len - rp + 1) >> 1;   // rows this parity accumulates (<=8)

    // deduplicated parallel gather
    int hidx[8];
    #pragma unroll
    for (int r = 0; r < 8; ++r) {
        int l = s + rp + 2 * r;
        l = (l < e) ? l : s;         // clamp -> unconditional (dups are L1 hits)
        hidx[r] = headb[l];
    }
    f32x2 vv[8];
    #pragma unroll
    for (int r = 0; r < 8; ++r)
        vv[r] = ((const f32x2*)(seqb + (size_t)hidx[r] * D))[col];
    f32x2 acc = (f32x2)(0.f);
    #pragma unroll
    for (int r = 0; r < 8; ++r)
        acc += (r < cnt) ? vv[r] : (f32x2)(0.f);

    pool[rp][c] = acc;
    __syncthreads();
    f32x2 v = (pool[0][c] + pool[1][c]) * (1.0f / (float)len);

    // fan-out writes (regular stores; 64-lane wave = 512 B contiguous)
    f32x2* outg = (f32x2*)out;       // rel rows: 768 f32x2 each
    size_t rowbase = (size_t)b * P;

    if (rp == 0) {
        // OBJ half of rows m*23 + r, granule offset col
        size_t q = (rowbase + (size_t)m * 23) * 768 + col;
        #pragma unroll
        for (int r = 0; r < 23; ++r) {
            outg[q] = v;
            q += 768;
        }
        if (chalf == 0 && c < 23) {
            int rr = c;
            int j = (rr < m) ? rr : rr + 1;
            float* o = out + (size_t)B * P * 2 * D
                     + (rowbase + (size_t)m * 23 + rr) * 5;
            o[0] = (float)b;
            o[1] = (float)s;
            o[2] = (float)e;
            o[3] = (float)emb[2 * j];
            o[4] = (float)emb[2 * j + 1];
        }
    } else {
        // SUB half: this mention is j == m; for each i != m, r = (m<i) ? m : m-1
        #pragma unroll
        for (int i = 0; i < M; ++i) {
            if (i == m) continue;
            int r = (m < i) ? m : m - 1;
            size_t row = rowbase + (size_t)i * 23 + r;
            outg[row * 768 + 384 + col] = v;
        }
    }
}

extern "C" void kernel_launch(void* const* d_in, const int* in_sizes, int n_in,
                              void* d_out, int out_size, void* d_ws, size_t ws_size,
                              hipStream_t stream) {
    const float* seq  = (const float*)d_in[0];
    const int*   head = (const int*)d_in[1];
    const int*   em   = (const int*)d_in[2];
    float* out = (float*)d_out;

    fused_kernel<<<B * M * 2, 384, 0, stream>>>(seq, head, em, out);  // 1536 blocks
}